// Round 26
// baseline (863.219 us; speedup 1.0000x reference)
//
#include <hip/hip_runtime.h>
#include <math.h>

// Problem constants (from reference): B=128, S=2048, D=16, K=8
constexpr int Dc = 16;
constexpr int Kc = 8;
constexpr int Ntot = 128 * 2048 * 16;
constexpr int NKNOT = 129;   // z-knots at j/128
constexpr int NSEG  = 128;

// ---------------------------------------------------------------------------
// R26: certified-table fast path, ALL hot state in LDS/registers.
// Ledger: R22-25 proved (a) d_ws hot reads fatal (~1.2ms), (b) global per-
// lane table gather slow, (c) per-element Halley with a partially-bad seed
// drags wave-max (R25: 206us > R21's 104). Fix: k1 does NO solving -- just
// 2 cubic-Hermite evals from a 33KB LDS table for CERTIFIED segments (the
// R22 certification: p>=1e-2, 5 probes, err_x<=1.5e-4, err_ld<=1.5e-3 ->
// certified-path error << bf16 quantum; produced absmax 0.25 in R22).
// Uncertified (~3-6%) compact to g_list_s; k1b solves them in DENSE waves
// (Halley-8, R21 acceptance/flat-strip); failures -> k2 bit-exact R13
// trajectory. k1 = 1024 persistent blocks (grid-stride x16) so the table
// loads once per block. No d_ws usage at all.
// ---------------------------------------------------------------------------
__device__ float4 g_tbl4[Dc * NKNOT];       // (x, 1/p, -logp, d(-logp)/dz)
__device__ unsigned int g_certfail[Dc * NSEG];
__device__ unsigned int g_certbits[64];     // 2048 segments / 32
__device__ unsigned int g_cnt_s, g_cnt_r;
__device__ unsigned int g_list_s[Ntot];
__device__ unsigned int g_list_r[Ntot];

__device__ __forceinline__ float cr_expf(float x) { return (float)exp((double)x); }
__device__ __forceinline__ float cr_logf(float x) { return (float)log((double)x); }

__device__ __forceinline__ float erf_xla_f32(float x) {
    x = fminf(fmaxf(x, -4.0f), 4.0f);
    float y = __fmul_rn(x, x);
    float a = -2.72614225801306e-10f;
    a = __fadd_rn(__fmul_rn(a, y),  2.77068142495902e-08f);
    a = __fadd_rn(__fmul_rn(a, y), -2.10102402082508e-06f);
    a = __fadd_rn(__fmul_rn(a, y), -5.69250639462346e-05f);
    a = __fadd_rn(__fmul_rn(a, y), -7.34990630326855e-04f);
    a = __fadd_rn(__fmul_rn(a, y), -2.95459980854025e-03f);
    a = __fadd_rn(__fmul_rn(a, y), -1.60960333262415e-02f);
    float b = -1.45660718464996e-05f;
    b = __fadd_rn(__fmul_rn(b, y), -2.13374055278905e-04f);
    b = __fadd_rn(__fmul_rn(b, y), -1.68282697438203e-03f);
    b = __fadd_rn(__fmul_rn(b, y), -7.37332916720468e-03f);
    b = __fadd_rn(__fmul_rn(b, y), -1.42647390514189e-02f);
    return __fdiv_rn(__fmul_rn(x, a), b);
}

// Giles (2012) single-precision erfinv.
__device__ __forceinline__ float erfinv_f32(float t) {
    float w = -__logf(fmaf(-t, t, 1.0f));
    float p;
    if (w < 5.0f) {
        w -= 2.5f;
        p = 2.81022636e-08f;
        p = fmaf(p, w, 3.43273939e-07f);
        p = fmaf(p, w, -3.5233877e-06f);
        p = fmaf(p, w, -4.39150654e-06f);
        p = fmaf(p, w, 2.1858087e-04f);
        p = fmaf(p, w, -1.25372503e-03f);
        p = fmaf(p, w, -4.17768164e-03f);
        p = fmaf(p, w, 2.46640727e-01f);
        p = fmaf(p, w, 1.50140941e+00f);
    } else {
        w = sqrtf(w) - 3.0f;
        p = -2.00214257e-04f;
        p = fmaf(p, w, 1.00950558e-04f);
        p = fmaf(p, w, 1.34934322e-03f);
        p = fmaf(p, w, -3.67342844e-03f);
        p = fmaf(p, w, 5.73950773e-03f);
        p = fmaf(p, w, -7.62246130e-03f);
        p = fmaf(p, w, 9.43887047e-03f);
        p = fmaf(p, w, 1.00167406e+00f);
        p = fmaf(p, w, 2.83297682e+00f);
    }
    return p * t;
}

struct Params {
    float muk[Kc], sk[Kc], rk[Kc], wk[Kc];
    float lb, ub;
};

// Per-thread prep -- byte-identical values to R13 (exact channel).
__device__ __forceinline__ void prep_params(int d, const float* __restrict__ logits,
                                            const float* __restrict__ mu,
                                            const float* __restrict__ logstd, Params& P)
{
    const float SQRT2F = 1.41421356237309515f;
    float lg[Kc];
#pragma unroll
    for (int k = 0; k < Kc; ++k) lg[k] = logits[k];
    float lmax = lg[0];
#pragma unroll
    for (int k = 1; k < Kc; ++k) lmax = fmaxf(lmax, lg[k]);
    float ew[Kc];
#pragma unroll
    for (int k = 0; k < Kc; ++k) ew[k] = cr_expf(__fsub_rn(lg[k], lmax));
    float wsum = ew[0];
#pragma unroll
    for (int k = 1; k < Kc; ++k) wsum = __fadd_rn(wsum, ew[k]);
#pragma unroll
    for (int k = 0; k < Kc; ++k) P.wk[k] = __fdiv_rn(ew[k], wsum);

    float ssum = 0.f;
#pragma unroll
    for (int k = 0; k < Kc; ++k) {
        P.muk[k] = mu[k * Dc + d];
        P.sk[k]  = cr_expf(logstd[k * Dc + d]);
        P.rk[k]  = (float)(1.0 / ((double)P.sk[k] * (double)SQRT2F));
        ssum     = __fadd_rn(ssum, P.sk[k]);
    }
    float m10 = __fmul_rn(10.0f, ssum);
    float lb = __fsub_rn(P.muk[0], m10);
    float ub = __fadd_rn(P.muk[0], m10);
#pragma unroll
    for (int k = 1; k < Kc; ++k) {
        lb = fminf(lb, __fsub_rn(P.muk[k], m10));
        ub = fmaxf(ub, __fadd_rn(P.muk[k], m10));
    }
    P.lb = lb; P.ub = ub;
}

// Bit-identical to R13's comparator evaluation (exact value channel).
__device__ __forceinline__ float Feval(float x, const Params& P) {
    float acc = 0.f;
#pragma unroll
    for (int k = 0; k < Kc; ++k) {
        float t   = __fmul_rn(__fsub_rn(x, P.muk[k]), P.rk[k]);
        float e   = erf_xla_f32(t);
        float cdf = __fmul_rn(0.5f, __fadd_rn(1.0f, e));
        acc = __fadd_rn(acc, __fmul_rn(cdf, P.wk[k]));
    }
    return acc;
}

// Bit-identical to R13's log-det epilogue.
__device__ __forceinline__ float logdet_exact(float x, const Params& P) {
    const float INV_SQRT_2PIF = 0.39894228040143267f;
    float p = 0.f;
#pragma unroll
    for (int k = 0; k < Kc; ++k) {
        float u   = __fdiv_rn(__fsub_rn(x, P.muk[k]), P.sk[k]);
        float q   = __fmul_rn(__fmul_rn(-0.5f, u), u);
        float pdf = __fmul_rn(cr_expf(q), __fdiv_rn(INV_SQRT_2PIF, P.sk[k]));
        p = __fadd_rn(p, __fmul_rn(pdf, P.wk[k]));
    }
    return -cr_logf(p);
}

// R13's exact trajectory (value-space bisection, reference update rule).
__device__ void traj_solve(float zv, const Params& P, float& xo, float& nldo) {
    float x = 0.f, lb = P.lb, ub = P.ub;
    int stable = 0;
    for (int it = 0; it < 200; ++it) {
        float acc = Feval(x, P);
        bool gt = acc > zv;
        float nx = __fmul_rn(__fadd_rn(x, gt ? lb : ub), 0.5f);
        if (gt) ub = x; else lb = x;
        stable = (nx == x) ? (stable + 1) : 0;
        x = nx;
        if (__all(stable >= 2)) break;
    }
    xo = x;
    nldo = logdet_exact(x, P);
}

// ---- smooth channel ----
struct SP {
    float muk[Kc], rk[Kc], ck[Kc], wh[Kc];
    float lb, ub, m, sig;
};

__device__ __forceinline__ void sp_from_params(const Params& P, SP& S) {
    const float INV_SQRT_2PIF = 0.39894228040143267f;
    float m = 0.f;
#pragma unroll
    for (int k = 0; k < Kc; ++k) {
        S.muk[k] = P.muk[k];
        S.rk[k]  = P.rk[k];
        S.ck[k]  = P.wk[k] * INV_SQRT_2PIF / P.sk[k];
        S.wh[k]  = 0.5f * P.wk[k];
        m = fmaf(P.wk[k], P.muk[k], m);
    }
    float var = 0.f;
#pragma unroll
    for (int k = 0; k < Kc; ++k) {
        float dm = P.muk[k] - m;
        var = fmaf(P.wk[k], fmaf(dm, dm, P.sk[k] * P.sk[k]), var);
    }
    S.m = m; S.sig = sqrtf(var);
    S.lb = P.lb; S.ub = P.ub;
}

__device__ __forceinline__ void smooth_eval(float x, const SP& S,
                                            float& F, float& den, float& f2) {
    F = 0.5f; den = 0.f; f2 = 0.f;
#pragma unroll
    for (int k = 0; k < Kc; ++k) {
        float t  = (x - S.muk[k]) * S.rk[k];
        float tc = fminf(fmaxf(t, -4.f), 4.f);
        float y  = tc * tc;
        float a = fmaf(-2.72614225801306e-10f, y,  2.77068142495902e-08f);
        a = fmaf(a, y, -2.10102402082508e-06f);
        a = fmaf(a, y, -5.69250639462346e-05f);
        a = fmaf(a, y, -7.34990630326855e-04f);
        a = fmaf(a, y, -2.95459980854025e-03f);
        a = fmaf(a, y, -1.60960333262415e-02f);
        float b = fmaf(-1.45660718464996e-05f, y, -2.13374055278905e-04f);
        b = fmaf(b, y, -1.68282697438203e-03f);
        b = fmaf(b, y, -7.37332916720468e-03f);
        b = fmaf(b, y, -1.42647390514189e-02f);
        float e = (tc * a) * __builtin_amdgcn_rcpf(b);
        F = fmaf(S.wh[k], e, F);
        float g = S.ck[k] * __expf(-t * t);
        den += g;
        f2 = fmaf(g, t * S.rk[k], f2);
    }
}

__device__ __forceinline__ float gauss_seed_sp(float zv, const SP& S) {
    const float SQRT2F = 1.41421356237309515f;
    float tt = fminf(fmaxf(2.f * zv - 1.f, -0.999999f), 0.999999f);
    return fmaf(S.sig * SQRT2F, erfinv_f32(tt), S.m);
}

// fixed-iteration safeguarded Halley; leaves final eval at x in F/den/f2.
__device__ void solve_fixed(float zv, const SP& S, float x0, int iters,
                            float& x, float& F, float& den, float& f2) {
    x = fminf(fmaxf(x0, S.lb + 1e-3f), S.ub - 1e-3f);
    float blo = S.lb, bhi = S.ub;
    for (int it = 0; it < iters; ++it) {
        smooth_eval(x, S, F, den, f2);
        float r = F - zv;
        bool gt = r > 0.f;
        if (gt) bhi = x; else blo = x;
        float invd = __builtin_amdgcn_rcpf(fmaxf(den, 1e-30f));
        float nstep = r * invd;
        float hden = fmaf(nstep * invd, f2, 1.0f);
        hden = fminf(fmaxf(hden, 0.5f), 2.0f);
        float xn = x - nstep * __builtin_amdgcn_rcpf(hden);
        if (!(xn > blo && xn < bhi)) xn = 0.5f * (blo + bhi);
        x = xn;
    }
    smooth_eval(x, S, F, den, f2);
}

__device__ __forceinline__ void hermite2(float u, float h, float4 K0, float4 K1,
                                         float& xv, float& ldv) {
    float u2 = u * u, u3 = u2 * u;
    float h00 = 2.f * u3 - 3.f * u2 + 1.f;
    float h10 = u3 - 2.f * u2 + u;
    float h01 = 3.f * u2 - 2.f * u3;
    float h11 = u3 - u2;
    xv  = h00 * K0.x + h10 * h * K0.y + h01 * K1.x + h11 * h * K1.y;
    ldv = h00 * K0.z + h10 * h * K0.w + h01 * K1.z + h11 * h * K1.w;
}

// ---- k0a: knot solve; zero counters/certfail/certbits ----
__global__ __launch_bounds__(256)
void k0a_knots(const float* __restrict__ logits, const float* __restrict__ mu,
               const float* __restrict__ logstd)
{
    int t = blockIdx.x * 256 + threadIdx.x;
    if (t == 0) { g_cnt_s = 0u; g_cnt_r = 0u; }
    if (t < 64) g_certbits[t] = 0u;
    if (t < Dc * NSEG) g_certfail[t] = 0u;
    if (t >= Dc * NKNOT) return;
    int d = t / NKNOT, j = t - d * NKNOT;
    Params P; prep_params(d, logits, mu, logstd, P);
    SP S; sp_from_params(P, S);
    float zv = (float)j * (1.0f / 128.0f);
    float x, F, den, f2;
    solve_fixed(zv, S, gauss_seed_sp(zv, S), 16, x, F, den, f2);
    bool ok = (den >= 5e-3f) && (fabsf(F - zv) <= 2e-5f);
    float s   = ok ? (1.0f / den) : -1.0f;
    float ld  = ok ? -__logf(den) : 0.f;
    float mld = ok ? (2.f * f2 / (den * den)) : 0.f;
    g_tbl4[t] = make_float4(x, s, ld, mld);
}

// ---- k0b: certify segments (5 probes each) ----
__global__ __launch_bounds__(256)
void k0b_cert(const float* __restrict__ logits, const float* __restrict__ mu,
              const float* __restrict__ logstd)
{
    int t = blockIdx.x * 256 + threadIdx.x;
    if (t >= Dc * NSEG * 5) return;
    int seg = t / 5, probe = t - seg * 5;
    int d = seg / NSEG, j = seg - d * NSEG;
    float4 K0 = g_tbl4[d * NKNOT + j], K1 = g_tbl4[d * NKNOT + j + 1];
    bool knots_ok = (K0.y > 0.f) && (K0.y <= 100.f) && (K1.y > 0.f) && (K1.y <= 100.f);
    if (!knots_ok) {
        if (probe == 0) atomicAdd(&g_certfail[seg], 1u);
        return;
    }
    const float h = 1.0f / 128.0f;
    float u  = (float)(probe + 1) * (1.0f / 6.0f);    // 1/6 .. 5/6
    float zv = ((float)j + u) * h;
    float xh, ldh;
    hermite2(u, h, K0, K1, xh, ldh);
    Params P; prep_params(d, logits, mu, logstd, P);
    SP S; sp_from_params(P, S);
    float x, F, den, f2;
    solve_fixed(zv, S, xh, 16, x, F, den, f2);
    bool ok = (den >= 1e-2f) && (fabsf(F - zv) <= 2e-5f)
           && (fabsf(x - xh) <= 1.5e-4f)
           && (fabsf(-__logf(den) - ldh) <= 1.5e-3f);
    if (!ok) atomicAdd(&g_certfail[seg], 1u);
}

// ---- k0c: fold certification into a bitmask ----
__global__ __launch_bounds__(256)
void k0c_pack()
{
    int seg = blockIdx.x * 256 + threadIdx.x;
    if (seg >= Dc * NSEG) return;
    int d = seg / NSEG, j = seg - d * NSEG;
    float4 K0 = g_tbl4[d * NKNOT + j], K1 = g_tbl4[d * NKNOT + j + 1];
    bool ok = (g_certfail[seg] == 0u)
           && (K0.y > 0.f) && (K0.y <= 100.f) && (K1.y > 0.f) && (K1.y <= 100.f);
    if (ok) atomicOr(&g_certbits[seg >> 5], 1u << (seg & 31));
}

// ---- k1: LDS-table Hermite fast path (no solver), persistent blocks ----
__global__ __launch_bounds__(256)
void k1_table(const float* __restrict__ z_in,
              float* __restrict__ out_x, float* __restrict__ out_nld)
{
    __shared__ float4 s_tbl[Dc * NKNOT];    // 33 KB
    __shared__ unsigned int s_cert[64];
    int tid = threadIdx.x;
    for (int t = tid; t < Dc * NKNOT; t += 256) s_tbl[t] = g_tbl4[t];
    if (tid < 64) s_cert[tid] = g_certbits[tid];
    __syncthreads();

    const float h = 1.0f / 128.0f;
    int stride = gridDim.x * 256;
    for (int i = blockIdx.x * 256 + tid; i < Ntot; i += stride) {
        int d = i & (Dc - 1);
        float zv = fminf(fmaxf(z_in[i], 0.f), 1.f);
        float zs = zv * 128.0f;
        int j = min((int)zs, 127);
        float u = zs - (float)j;
        int seg = d * NSEG + j;
        bool cert = (s_cert[seg >> 5] >> (seg & 31)) & 1u;
        float xv = 0.f, ldv = 0.f;
        if (cert) {
            float4 K0 = s_tbl[d * NKNOT + j], K1 = s_tbl[d * NKNOT + j + 1];
            hermite2(u, h, K0, K1, xv, ldv);
        } else {
            unsigned int idx = atomicAdd(&g_cnt_s, 1u);
            g_list_s[idx] = (unsigned int)i;
        }
        out_x[i]   = xv;
        out_nld[i] = ldv;
    }
}

// ---- k1b: dense Halley over the slow list (R21 loop, LDS table seed) ----
__global__ __launch_bounds__(256)
void k1b_slow(const float* __restrict__ z_in, const float* __restrict__ logits,
              const float* __restrict__ mu, const float* __restrict__ logstd,
              float* __restrict__ out_x, float* __restrict__ out_nld)
{
    const float SQRT2F = 1.41421356237309515f;
    const float INV_SQRT_2PIF = 0.39894228040143267f;
    __shared__ float4 s_tbl[Dc * NKNOT];    // 33 KB (seed: .x, .y)
    __shared__ float s_ew[Kc], s_wk[Kc];
    __shared__ float s_mu[Kc][Dc], s_s[Kc][Dc], s_r[Kc][Dc], s_c[Kc][Dc];
    __shared__ float s_lb[Dc], s_ub[Dc], s_m[Dc], s_sig[Dc];
    int tid = threadIdx.x;
    for (int t = tid; t < Dc * NKNOT; t += 256) s_tbl[t] = g_tbl4[t];
    if (tid < Kc) {
        float lmax = logits[0];
#pragma unroll
        for (int k = 1; k < Kc; ++k) lmax = fmaxf(lmax, logits[k]);
        s_ew[tid] = cr_expf(__fsub_rn(logits[tid], lmax));
    }
    if (tid < Kc * Dc) {
        int k = tid >> 4, d = tid & 15;
        s_mu[k][d] = mu[k * Dc + d];
        float s = cr_expf(logstd[k * Dc + d]);
        s_s[k][d] = s;
        s_r[k][d] = (float)(1.0 / ((double)s * (double)SQRT2F));
    }
    __syncthreads();
    if (tid < Kc) {
        float wsum = s_ew[0];
#pragma unroll
        for (int k = 1; k < Kc; ++k) wsum = __fadd_rn(wsum, s_ew[k]);
        s_wk[tid] = __fdiv_rn(s_ew[tid], wsum);
    }
    __syncthreads();
    if (tid < Dc) {
        float ssum = 0.f, m = 0.f;
#pragma unroll
        for (int k = 0; k < Kc; ++k) {
            ssum = __fadd_rn(ssum, s_s[k][tid]);
            m    = fmaf(s_wk[k], s_mu[k][tid], m);
        }
        float var = 0.f;
#pragma unroll
        for (int k = 0; k < Kc; ++k) {
            float dm = s_mu[k][tid] - m;
            var = fmaf(s_wk[k], fmaf(dm, dm, s_s[k][tid] * s_s[k][tid]), var);
        }
        s_m[tid] = m; s_sig[tid] = sqrtf(var);
        float m10 = __fmul_rn(10.0f, ssum);
        float lb = __fsub_rn(s_mu[0][tid], m10);
        float ub = __fadd_rn(s_mu[0][tid], m10);
#pragma unroll
        for (int k = 1; k < Kc; ++k) {
            lb = fminf(lb, __fsub_rn(s_mu[k][tid], m10));
            ub = fmaxf(ub, __fadd_rn(s_mu[k][tid], m10));
        }
        s_lb[tid] = lb; s_ub[tid] = ub;
    }
    if (tid < Kc * Dc) {
        int k = tid >> 4, d = tid & 15;
        s_c[k][d] = s_wk[k] * INV_SQRT_2PIF / s_s[k][d];
    }
    __syncthreads();

    unsigned int n = g_cnt_s;
    unsigned int stride = gridDim.x * 256;
    for (unsigned int base = blockIdx.x * 256; base < n; base += stride) {
        unsigned int jj = base + tid;
        bool valid = jj < n;
        int i = valid ? (int)g_list_s[jj] : 0;
        int d = i & (Dc - 1);
        float zv = valid ? fminf(fmaxf(z_in[i], 0.f), 1.f) : 0.5f;
        float muk[Kc], rk[Kc], ck[Kc], wh[Kc];
#pragma unroll
        for (int k = 0; k < Kc; ++k) {
            muk[k] = s_mu[k][d]; rk[k] = s_r[k][d];
            ck[k]  = s_c[k][d];  wh[k] = 0.5f * s_wk[k];
        }
        float lb = s_lb[d], ub = s_ub[d];
        // seed: x-Hermite from LDS table if knots usable, else Gaussian
        float zs = zv * 128.0f;
        int sj = min((int)zs, 127);
        float su = zs - (float)sj;
        float4 K0 = s_tbl[d * NKNOT + sj], K1 = s_tbl[d * NKNOT + sj + 1];
        float x;
        if (K0.y > 0.f && K1.y > 0.f) {
            const float h = 1.0f / 128.0f;
            float u2 = su * su, u3 = u2 * su;
            x = (2.f * u3 - 3.f * u2 + 1.f) * K0.x
              + (u3 - 2.f * u2 + su) * h * K0.y
              + (3.f * u2 - 2.f * u3) * K1.x
              + (u3 - u2) * h * K1.y;
        } else {
            float tt = fminf(fmaxf(2.f * zv - 1.f, -0.999999f), 0.999999f);
            x = fmaf(s_sig[d] * SQRT2F, erfinv_f32(tt), s_m[d]);
        }
        x = fminf(fmaxf(x, lb + 1e-3f), ub - 1e-3f);

        float blo = lb, bhi = ub;
        float acc = 0.f, den = 0.f;
        bool conv = !valid, flat = false;
#pragma unroll 1
        for (int it = 0; it < 8; ++it) {
            acc = 0.5f; den = 0.f;
            float f2 = 0.f;
#pragma unroll
            for (int k = 0; k < Kc; ++k) {
                float t  = (x - muk[k]) * rk[k];
                float tc = fminf(fmaxf(t, -4.f), 4.f);
                float y  = tc * tc;
                float a = fmaf(-2.72614225801306e-10f, y,  2.77068142495902e-08f);
                a = fmaf(a, y, -2.10102402082508e-06f);
                a = fmaf(a, y, -5.69250639462346e-05f);
                a = fmaf(a, y, -7.34990630326855e-04f);
                a = fmaf(a, y, -2.95459980854025e-03f);
                a = fmaf(a, y, -1.60960333262415e-02f);
                float b = fmaf(-1.45660718464996e-05f, y, -2.13374055278905e-04f);
                b = fmaf(b, y, -1.68282697438203e-03f);
                b = fmaf(b, y, -7.37332916720468e-03f);
                b = fmaf(b, y, -1.42647390514189e-02f);
                float e = (tc * a) * __builtin_amdgcn_rcpf(b);
                acc = fmaf(wh[k], e, acc);
                float g = ck[k] * __expf(-t * t);
                den = den + g;
                f2  = fmaf(g, t * rk[k], f2);
            }
            float r = acc - zv;
            conv = conv || (fabsf(r) <= 1.5e-3f * den);
            flat = flat || ((den < 1e-3f) && (it >= 1));
            bool active = !(conv || flat);
            if (__all(!active)) break;
            if (active) {
                bool gt = r > 0.f;
                if (gt) bhi = x; else blo = x;
                float invd = __builtin_amdgcn_rcpf(den);
                float nstep = r * invd;
                float hden = fmaf(nstep * invd, f2, 1.0f);
                hden = fminf(fmaxf(hden, 0.5f), 2.0f);
                float xn = x - nstep * __builtin_amdgcn_rcpf(hden);
                if (!(xn > blo && xn < bhi)) xn = 0.5f * (blo + bhi);
                x = xn;
            }
        }
        if (valid) {
            bool rescue = (!conv) || (den < 1e-3f);
            if (!rescue) {
                out_x[i]   = x;
                out_nld[i] = -__logf(den);
            } else {
                unsigned int idx = atomicAdd(&g_cnt_r, 1u);
                g_list_r[idx] = (unsigned int)i;
            }
        }
    }
}

// ---- k2: bit-exact R13 trajectory for rescue lanes ----
__global__ __launch_bounds__(256)
void k2_rescue(const float* __restrict__ z_in, const float* __restrict__ logits,
               const float* __restrict__ mu, const float* __restrict__ logstd,
               float* __restrict__ out_x, float* __restrict__ out_nld)
{
    unsigned int n = g_cnt_r;
    for (unsigned int j = blockIdx.x * 256 + threadIdx.x; j < n;
         j += gridDim.x * 256) {
        int i = (int)g_list_r[j];
        Params P;
        prep_params(i & (Dc - 1), logits, mu, logstd, P);
        float zv = fminf(fmaxf(z_in[i], 0.f), 1.f);
        float x, nld;
        traj_solve(zv, P, x, nld);
        out_x[i]   = x;
        out_nld[i] = nld;
    }
}

extern "C" void kernel_launch(void* const* d_in, const int* in_sizes, int n_in,
                              void* d_out, int out_size, void* d_ws, size_t ws_size,
                              hipStream_t stream) {
    const float* z      = (const float*)d_in[0];
    const float* logits = (const float*)d_in[1];
    const float* mu     = (const float*)d_in[2];
    const float* logstd = (const float*)d_in[3];
    float* out_x   = (float*)d_out;
    float* out_nld = (float*)d_out + Ntot;

    k0a_knots<<<(Dc * NKNOT + 255) / 256, 256, 0, stream>>>(logits, mu, logstd);
    k0b_cert<<<(Dc * NSEG * 5 + 255) / 256, 256, 0, stream>>>(logits, mu, logstd);
    k0c_pack<<<(Dc * NSEG + 255) / 256, 256, 0, stream>>>();
    k1_table<<<1024, 256, 0, stream>>>(z, out_x, out_nld);
    k1b_slow<<<512, 256, 0, stream>>>(z, logits, mu, logstd, out_x, out_nld);
    k2_rescue<<<512, 256, 0, stream>>>(z, logits, mu, logstd, out_x, out_nld);
}

// Round 27
// 181.585 us; speedup vs baseline: 4.7538x; 4.7538x over previous
//
#include <hip/hip_runtime.h>
#include <math.h>

// Problem constants (from reference): B=128, S=2048, D=16, K=8
constexpr int Dc = 16;
constexpr int Kc = 8;
constexpr int Ntot = 128 * 2048 * 16;
constexpr int NKNOT = 129;   // z-knots at j/128
constexpr int NSEG  = 128;

// ---------------------------------------------------------------------------
// R27: atomic-free fast path (isolation test + fix).
// R26's datum: k1 at 750us with table in LDS == R23/24 with global table ->
// table access innocent. Remaining suspect: the per-wave same-address atomic
// +dependent list store, EXPOSED (no compute to hide under; ~26% slow lanes
// measured -> nearly every wave pays it). R19-21 had the same atomic hidden
// under ~2000cyc of solver compute.
//  k1: table Hermite for certified segs; uncertified -> write NaN sentinel.
//      ZERO atomics, zero lists.
//  k1b_scan: block-aggregated compaction of sentinels (1 atomic / 1024 el).
//  k1c: dense Halley-8 over compacted list; linear seed CLAMPED into the
//       segment's own [K0.x,K1.x] monotone bracket (no Hermite overshoot);
//       R21 acceptance (resid<=1.5e-3*den, den>=1e-3) + flat-strip.
//  k2: bit-exact R13 trajectory for rescue lanes (owns absmax 0.25).
// Cert gates: p>=3e-3 (was 1e-2; budget 40*1.5e-4+1.5e-3 << 0.0625 bf16
// quantum), err_x<=1.5e-4, err_ld<=1.5e-3, 5 probes (R22-proven scheme).
// ---------------------------------------------------------------------------
__device__ float4 g_tbl4[Dc * NKNOT];       // (x, 1/p, -logp, d(-logp)/dz)
__device__ unsigned int g_certfail[Dc * NSEG];
__device__ unsigned int g_certbits[64];     // 2048 segments / 32
__device__ unsigned int g_cnt_s, g_cnt_r;
__device__ unsigned int g_list_s[Ntot];
__device__ unsigned int g_list_r[Ntot];

__device__ __forceinline__ float cr_expf(float x) { return (float)exp((double)x); }
__device__ __forceinline__ float cr_logf(float x) { return (float)log((double)x); }

__device__ __forceinline__ float erf_xla_f32(float x) {
    x = fminf(fmaxf(x, -4.0f), 4.0f);
    float y = __fmul_rn(x, x);
    float a = -2.72614225801306e-10f;
    a = __fadd_rn(__fmul_rn(a, y),  2.77068142495902e-08f);
    a = __fadd_rn(__fmul_rn(a, y), -2.10102402082508e-06f);
    a = __fadd_rn(__fmul_rn(a, y), -5.69250639462346e-05f);
    a = __fadd_rn(__fmul_rn(a, y), -7.34990630326855e-04f);
    a = __fadd_rn(__fmul_rn(a, y), -2.95459980854025e-03f);
    a = __fadd_rn(__fmul_rn(a, y), -1.60960333262415e-02f);
    float b = -1.45660718464996e-05f;
    b = __fadd_rn(__fmul_rn(b, y), -2.13374055278905e-04f);
    b = __fadd_rn(__fmul_rn(b, y), -1.68282697438203e-03f);
    b = __fadd_rn(__fmul_rn(b, y), -7.37332916720468e-03f);
    b = __fadd_rn(__fmul_rn(b, y), -1.42647390514189e-02f);
    return __fdiv_rn(__fmul_rn(x, a), b);
}

// Giles (2012) single-precision erfinv.
__device__ __forceinline__ float erfinv_f32(float t) {
    float w = -__logf(fmaf(-t, t, 1.0f));
    float p;
    if (w < 5.0f) {
        w -= 2.5f;
        p = 2.81022636e-08f;
        p = fmaf(p, w, 3.43273939e-07f);
        p = fmaf(p, w, -3.5233877e-06f);
        p = fmaf(p, w, -4.39150654e-06f);
        p = fmaf(p, w, 2.1858087e-04f);
        p = fmaf(p, w, -1.25372503e-03f);
        p = fmaf(p, w, -4.17768164e-03f);
        p = fmaf(p, w, 2.46640727e-01f);
        p = fmaf(p, w, 1.50140941e+00f);
    } else {
        w = sqrtf(w) - 3.0f;
        p = -2.00214257e-04f;
        p = fmaf(p, w, 1.00950558e-04f);
        p = fmaf(p, w, 1.34934322e-03f);
        p = fmaf(p, w, -3.67342844e-03f);
        p = fmaf(p, w, 5.73950773e-03f);
        p = fmaf(p, w, -7.62246130e-03f);
        p = fmaf(p, w, 9.43887047e-03f);
        p = fmaf(p, w, 1.00167406e+00f);
        p = fmaf(p, w, 2.83297682e+00f);
    }
    return p * t;
}

struct Params {
    float muk[Kc], sk[Kc], rk[Kc], wk[Kc];
    float lb, ub;
};

// Per-thread prep -- byte-identical values to R13 (exact channel).
__device__ __forceinline__ void prep_params(int d, const float* __restrict__ logits,
                                            const float* __restrict__ mu,
                                            const float* __restrict__ logstd, Params& P)
{
    const float SQRT2F = 1.41421356237309515f;
    float lg[Kc];
#pragma unroll
    for (int k = 0; k < Kc; ++k) lg[k] = logits[k];
    float lmax = lg[0];
#pragma unroll
    for (int k = 1; k < Kc; ++k) lmax = fmaxf(lmax, lg[k]);
    float ew[Kc];
#pragma unroll
    for (int k = 0; k < Kc; ++k) ew[k] = cr_expf(__fsub_rn(lg[k], lmax));
    float wsum = ew[0];
#pragma unroll
    for (int k = 1; k < Kc; ++k) wsum = __fadd_rn(wsum, ew[k]);
#pragma unroll
    for (int k = 0; k < Kc; ++k) P.wk[k] = __fdiv_rn(ew[k], wsum);

    float ssum = 0.f;
#pragma unroll
    for (int k = 0; k < Kc; ++k) {
        P.muk[k] = mu[k * Dc + d];
        P.sk[k]  = cr_expf(logstd[k * Dc + d]);
        P.rk[k]  = (float)(1.0 / ((double)P.sk[k] * (double)SQRT2F));
        ssum     = __fadd_rn(ssum, P.sk[k]);
    }
    float m10 = __fmul_rn(10.0f, ssum);
    float lb = __fsub_rn(P.muk[0], m10);
    float ub = __fadd_rn(P.muk[0], m10);
#pragma unroll
    for (int k = 1; k < Kc; ++k) {
        lb = fminf(lb, __fsub_rn(P.muk[k], m10));
        ub = fmaxf(ub, __fadd_rn(P.muk[k], m10));
    }
    P.lb = lb; P.ub = ub;
}

// Bit-identical to R13's comparator evaluation (exact value channel).
__device__ __forceinline__ float Feval(float x, const Params& P) {
    float acc = 0.f;
#pragma unroll
    for (int k = 0; k < Kc; ++k) {
        float t   = __fmul_rn(__fsub_rn(x, P.muk[k]), P.rk[k]);
        float e   = erf_xla_f32(t);
        float cdf = __fmul_rn(0.5f, __fadd_rn(1.0f, e));
        acc = __fadd_rn(acc, __fmul_rn(cdf, P.wk[k]));
    }
    return acc;
}

// Bit-identical to R13's log-det epilogue.
__device__ __forceinline__ float logdet_exact(float x, const Params& P) {
    const float INV_SQRT_2PIF = 0.39894228040143267f;
    float p = 0.f;
#pragma unroll
    for (int k = 0; k < Kc; ++k) {
        float u   = __fdiv_rn(__fsub_rn(x, P.muk[k]), P.sk[k]);
        float q   = __fmul_rn(__fmul_rn(-0.5f, u), u);
        float pdf = __fmul_rn(cr_expf(q), __fdiv_rn(INV_SQRT_2PIF, P.sk[k]));
        p = __fadd_rn(p, __fmul_rn(pdf, P.wk[k]));
    }
    return -cr_logf(p);
}

// R13's exact trajectory (value-space bisection, reference update rule).
__device__ void traj_solve(float zv, const Params& P, float& xo, float& nldo) {
    float x = 0.f, lb = P.lb, ub = P.ub;
    int stable = 0;
    for (int it = 0; it < 200; ++it) {
        float acc = Feval(x, P);
        bool gt = acc > zv;
        float nx = __fmul_rn(__fadd_rn(x, gt ? lb : ub), 0.5f);
        if (gt) ub = x; else lb = x;
        stable = (nx == x) ? (stable + 1) : 0;
        x = nx;
        if (__all(stable >= 2)) break;
    }
    xo = x;
    nldo = logdet_exact(x, P);
}

// ---- smooth channel ----
struct SP {
    float muk[Kc], rk[Kc], ck[Kc], wh[Kc];
    float lb, ub, m, sig;
};

__device__ __forceinline__ void sp_from_params(const Params& P, SP& S) {
    const float INV_SQRT_2PIF = 0.39894228040143267f;
    float m = 0.f;
#pragma unroll
    for (int k = 0; k < Kc; ++k) {
        S.muk[k] = P.muk[k];
        S.rk[k]  = P.rk[k];
        S.ck[k]  = P.wk[k] * INV_SQRT_2PIF / P.sk[k];
        S.wh[k]  = 0.5f * P.wk[k];
        m = fmaf(P.wk[k], P.muk[k], m);
    }
    float var = 0.f;
#pragma unroll
    for (int k = 0; k < Kc; ++k) {
        float dm = P.muk[k] - m;
        var = fmaf(P.wk[k], fmaf(dm, dm, P.sk[k] * P.sk[k]), var);
    }
    S.m = m; S.sig = sqrtf(var);
    S.lb = P.lb; S.ub = P.ub;
}

__device__ __forceinline__ void smooth_eval(float x, const SP& S,
                                            float& F, float& den, float& f2) {
    F = 0.5f; den = 0.f; f2 = 0.f;
#pragma unroll
    for (int k = 0; k < Kc; ++k) {
        float t  = (x - S.muk[k]) * S.rk[k];
        float tc = fminf(fmaxf(t, -4.f), 4.f);
        float y  = tc * tc;
        float a = fmaf(-2.72614225801306e-10f, y,  2.77068142495902e-08f);
        a = fmaf(a, y, -2.10102402082508e-06f);
        a = fmaf(a, y, -5.69250639462346e-05f);
        a = fmaf(a, y, -7.34990630326855e-04f);
        a = fmaf(a, y, -2.95459980854025e-03f);
        a = fmaf(a, y, -1.60960333262415e-02f);
        float b = fmaf(-1.45660718464996e-05f, y, -2.13374055278905e-04f);
        b = fmaf(b, y, -1.68282697438203e-03f);
        b = fmaf(b, y, -7.37332916720468e-03f);
        b = fmaf(b, y, -1.42647390514189e-02f);
        float e = (tc * a) * __builtin_amdgcn_rcpf(b);
        F = fmaf(S.wh[k], e, F);
        float g = S.ck[k] * __expf(-t * t);
        den += g;
        f2 = fmaf(g, t * S.rk[k], f2);
    }
}

__device__ __forceinline__ float gauss_seed_sp(float zv, const SP& S) {
    const float SQRT2F = 1.41421356237309515f;
    float tt = fminf(fmaxf(2.f * zv - 1.f, -0.999999f), 0.999999f);
    return fmaf(S.sig * SQRT2F, erfinv_f32(tt), S.m);
}

// fixed-iteration safeguarded Halley; leaves final eval at x in F/den/f2.
__device__ void solve_fixed(float zv, const SP& S, float x0, int iters,
                            float& x, float& F, float& den, float& f2) {
    x = fminf(fmaxf(x0, S.lb + 1e-3f), S.ub - 1e-3f);
    float blo = S.lb, bhi = S.ub;
    for (int it = 0; it < iters; ++it) {
        smooth_eval(x, S, F, den, f2);
        float r = F - zv;
        bool gt = r > 0.f;
        if (gt) bhi = x; else blo = x;
        float invd = __builtin_amdgcn_rcpf(fmaxf(den, 1e-30f));
        float nstep = r * invd;
        float hden = fmaf(nstep * invd, f2, 1.0f);
        hden = fminf(fmaxf(hden, 0.5f), 2.0f);
        float xn = x - nstep * __builtin_amdgcn_rcpf(hden);
        if (!(xn > blo && xn < bhi)) xn = 0.5f * (blo + bhi);
        x = xn;
    }
    smooth_eval(x, S, F, den, f2);
}

__device__ __forceinline__ void hermite2(float u, float h, float4 K0, float4 K1,
                                         float& xv, float& ldv) {
    float u2 = u * u, u3 = u2 * u;
    float h00 = 2.f * u3 - 3.f * u2 + 1.f;
    float h10 = u3 - 2.f * u2 + u;
    float h01 = 3.f * u2 - 2.f * u3;
    float h11 = u3 - u2;
    xv  = h00 * K0.x + h10 * h * K0.y + h01 * K1.x + h11 * h * K1.y;
    ldv = h00 * K0.z + h10 * h * K0.w + h01 * K1.z + h11 * h * K1.w;
}

// ---- k0a: knot solve; zero counters/certfail/certbits ----
__global__ __launch_bounds__(256)
void k0a_knots(const float* __restrict__ logits, const float* __restrict__ mu,
               const float* __restrict__ logstd)
{
    int t = blockIdx.x * 256 + threadIdx.x;
    if (t == 0) { g_cnt_s = 0u; g_cnt_r = 0u; }
    if (t < 64) g_certbits[t] = 0u;
    if (t < Dc * NSEG) g_certfail[t] = 0u;
    if (t >= Dc * NKNOT) return;
    int d = t / NKNOT, j = t - d * NKNOT;
    Params P; prep_params(d, logits, mu, logstd, P);
    SP S; sp_from_params(P, S);
    float zv = (float)j * (1.0f / 128.0f);
    float x, F, den, f2;
    solve_fixed(zv, S, gauss_seed_sp(zv, S), 16, x, F, den, f2);
    bool ok = (den >= 1e-3f) && (fabsf(F - zv) <= 2e-5f);
    float s   = ok ? (1.0f / den) : -1.0f;
    float ld  = ok ? -__logf(den) : 0.f;
    float mld = ok ? (2.f * f2 / (den * den)) : 0.f;
    g_tbl4[t] = make_float4(x, s, ld, mld);
}

// ---- k0b: certify segments (5 probes each) ----
__global__ __launch_bounds__(256)
void k0b_cert(const float* __restrict__ logits, const float* __restrict__ mu,
              const float* __restrict__ logstd)
{
    int t = blockIdx.x * 256 + threadIdx.x;
    if (t >= Dc * NSEG * 5) return;
    int seg = t / 5, probe = t - seg * 5;
    int d = seg / NSEG, j = seg - d * NSEG;
    float4 K0 = g_tbl4[d * NKNOT + j], K1 = g_tbl4[d * NKNOT + j + 1];
    bool knots_ok = (K0.y > 0.f) && (K0.y <= 1000.f) && (K1.y > 0.f) && (K1.y <= 1000.f);
    if (!knots_ok) {
        if (probe == 0) atomicAdd(&g_certfail[seg], 1u);
        return;
    }
    const float h = 1.0f / 128.0f;
    float u  = (float)(probe + 1) * (1.0f / 6.0f);    // 1/6 .. 5/6
    float zv = ((float)j + u) * h;
    float xh, ldh;
    hermite2(u, h, K0, K1, xh, ldh);
    Params P; prep_params(d, logits, mu, logstd, P);
    SP S; sp_from_params(P, S);
    float x, F, den, f2;
    solve_fixed(zv, S, xh, 16, x, F, den, f2);
    bool ok = (den >= 3e-3f) && (fabsf(F - zv) <= 2e-5f)
           && (fabsf(x - xh) <= 1.5e-4f)
           && (fabsf(-__logf(den) - ldh) <= 1.5e-3f);
    if (!ok) atomicAdd(&g_certfail[seg], 1u);
}

// ---- k0c: fold certification into a bitmask ----
__global__ __launch_bounds__(256)
void k0c_pack()
{
    int seg = blockIdx.x * 256 + threadIdx.x;
    if (seg >= Dc * NSEG) return;
    int d = seg / NSEG, j = seg - d * NSEG;
    float4 K0 = g_tbl4[d * NKNOT + j], K1 = g_tbl4[d * NKNOT + j + 1];
    bool ok = (g_certfail[seg] == 0u)
           && (K0.y > 0.f) && (K0.y <= 1000.f) && (K1.y > 0.f) && (K1.y <= 1000.f);
    if (ok) atomicOr(&g_certbits[seg >> 5], 1u << (seg & 31));
}

// ---- k1: LDS-table Hermite fast path. NO atomics: NaN sentinel ----
__global__ __launch_bounds__(256)
void k1_table(const float* __restrict__ z_in,
              float* __restrict__ out_x, float* __restrict__ out_nld)
{
    __shared__ float4 s_tbl[Dc * NKNOT];    // 33 KB
    __shared__ unsigned int s_cert[64];
    int tid = threadIdx.x;
    for (int t = tid; t < Dc * NKNOT; t += 256) s_tbl[t] = g_tbl4[t];
    if (tid < 64) s_cert[tid] = g_certbits[tid];
    __syncthreads();

    const float h = 1.0f / 128.0f;
    const float NANF = __uint_as_float(0x7FC00000u);
    int stride = gridDim.x * 256;
    for (int i = blockIdx.x * 256 + tid; i < Ntot; i += stride) {
        int d = i & (Dc - 1);
        float zv = fminf(fmaxf(z_in[i], 0.f), 1.f);
        float zs = zv * 128.0f;
        int j = min((int)zs, 127);
        float u = zs - (float)j;
        int seg = d * NSEG + j;
        bool cert = (s_cert[seg >> 5] >> (seg & 31)) & 1u;
        float xv = NANF, ldv = 0.f;
        if (cert) {
            float4 K0 = s_tbl[d * NKNOT + j], K1 = s_tbl[d * NKNOT + j + 1];
            hermite2(u, h, K0, K1, xv, ldv);
        }
        out_x[i]   = xv;
        out_nld[i] = ldv;
    }
}

// ---- k1b_scan: block-aggregated compaction of NaN sentinels ----
// 4096 blocks x 256 threads, 4 elements/thread (coalesced passes).
__global__ __launch_bounds__(256)
void k1b_scan(const float* __restrict__ out_x)
{
    __shared__ unsigned int s_buf[1024];
    __shared__ unsigned int s_cnt, s_base;
    int tid = threadIdx.x;
    if (tid == 0) s_cnt = 0u;
    __syncthreads();
    int base = blockIdx.x * 1024;
#pragma unroll
    for (int p = 0; p < 4; ++p) {
        int i = base + p * 256 + tid;
        if (i < Ntot && isnan(out_x[i])) {
            unsigned int sp = atomicAdd(&s_cnt, 1u);
            s_buf[sp] = (unsigned int)i;
        }
    }
    __syncthreads();
    if (tid == 0) s_base = (s_cnt > 0u) ? atomicAdd(&g_cnt_s, s_cnt) : 0u;
    __syncthreads();
    unsigned int n = s_cnt, b = s_base;
    for (unsigned int t = tid; t < n; t += 256) g_list_s[b + t] = s_buf[t];
}

// ---- k1c: dense Halley over the compacted list ----
__global__ __launch_bounds__(256)
void k1c_slow(const float* __restrict__ z_in, const float* __restrict__ logits,
              const float* __restrict__ mu, const float* __restrict__ logstd,
              float* __restrict__ out_x, float* __restrict__ out_nld)
{
    const float SQRT2F = 1.41421356237309515f;
    const float INV_SQRT_2PIF = 0.39894228040143267f;
    __shared__ float4 s_tbl[Dc * NKNOT];    // 33 KB (seed bracket)
    __shared__ float s_ew[Kc], s_wk[Kc];
    __shared__ float s_mu[Kc][Dc], s_s[Kc][Dc], s_r[Kc][Dc], s_c[Kc][Dc];
    __shared__ float s_lb[Dc], s_ub[Dc], s_m[Dc], s_sig[Dc];
    int tid = threadIdx.x;
    for (int t = tid; t < Dc * NKNOT; t += 256) s_tbl[t] = g_tbl4[t];
    if (tid < Kc) {
        float lmax = logits[0];
#pragma unroll
        for (int k = 1; k < Kc; ++k) lmax = fmaxf(lmax, logits[k]);
        s_ew[tid] = cr_expf(__fsub_rn(logits[tid], lmax));
    }
    if (tid < Kc * Dc) {
        int k = tid >> 4, d = tid & 15;
        s_mu[k][d] = mu[k * Dc + d];
        float s = cr_expf(logstd[k * Dc + d]);
        s_s[k][d] = s;
        s_r[k][d] = (float)(1.0 / ((double)s * (double)SQRT2F));
    }
    __syncthreads();
    if (tid < Kc) {
        float wsum = s_ew[0];
#pragma unroll
        for (int k = 1; k < Kc; ++k) wsum = __fadd_rn(wsum, s_ew[k]);
        s_wk[tid] = __fdiv_rn(s_ew[tid], wsum);
    }
    __syncthreads();
    if (tid < Dc) {
        float ssum = 0.f, m = 0.f;
#pragma unroll
        for (int k = 0; k < Kc; ++k) {
            ssum = __fadd_rn(ssum, s_s[k][tid]);
            m    = fmaf(s_wk[k], s_mu[k][tid], m);
        }
        float var = 0.f;
#pragma unroll
        for (int k = 0; k < Kc; ++k) {
            float dm = s_mu[k][tid] - m;
            var = fmaf(s_wk[k], fmaf(dm, dm, s_s[k][tid] * s_s[k][tid]), var);
        }
        s_m[tid] = m; s_sig[tid] = sqrtf(var);
        float m10 = __fmul_rn(10.0f, ssum);
        float lb = __fsub_rn(s_mu[0][tid], m10);
        float ub = __fadd_rn(s_mu[0][tid], m10);
#pragma unroll
        for (int k = 1; k < Kc; ++k) {
            lb = fminf(lb, __fsub_rn(s_mu[k][tid], m10));
            ub = fmaxf(ub, __fadd_rn(s_mu[k][tid], m10));
        }
        s_lb[tid] = lb; s_ub[tid] = ub;
    }
    if (tid < Kc * Dc) {
        int k = tid >> 4, d = tid & 15;
        s_c[k][d] = s_wk[k] * INV_SQRT_2PIF / s_s[k][d];
    }
    __syncthreads();

    unsigned int n = g_cnt_s;
    unsigned int stride = gridDim.x * 256;
    for (unsigned int base = blockIdx.x * 256; base < n; base += stride) {
        unsigned int jj = base + tid;
        bool valid = jj < n;
        int i = valid ? (int)g_list_s[jj] : 0;
        int d = i & (Dc - 1);
        float zv = valid ? fminf(fmaxf(z_in[i], 0.f), 1.f) : 0.5f;
        float muk[Kc], rk[Kc], ck[Kc], wh[Kc];
#pragma unroll
        for (int k = 0; k < Kc; ++k) {
            muk[k] = s_mu[k][d]; rk[k] = s_r[k][d];
            ck[k]  = s_c[k][d];  wh[k] = 0.5f * s_wk[k];
        }
        float lb = s_lb[d], ub = s_ub[d];
        // seed + tight bracket from the segment's knots (monotone); else Gaussian
        float zs = zv * 128.0f;
        int sj = min((int)zs, 127);
        float su = zs - (float)sj;
        float4 K0 = s_tbl[d * NKNOT + sj], K1 = s_tbl[d * NKNOT + sj + 1];
        float x, blo, bhi;
        if (K0.y > 0.f && K1.y > 0.f) {
            float w = K1.x - K0.x;
            x   = fmaf(su, w, K0.x);              // linear, no overshoot
            blo = fmaxf(K0.x - 0.1f * w - 1e-4f, lb);
            bhi = fminf(K1.x + 0.1f * w + 1e-4f, ub);
        } else {
            float tt = fminf(fmaxf(2.f * zv - 1.f, -0.999999f), 0.999999f);
            x   = fmaf(s_sig[d] * SQRT2F, erfinv_f32(tt), s_m[d]);
            blo = lb; bhi = ub;
        }
        x = fminf(fmaxf(x, blo), bhi);

        float acc = 0.f, den = 0.f;
        bool conv = !valid, flat = false;
#pragma unroll 1
        for (int it = 0; it < 8; ++it) {
            acc = 0.5f; den = 0.f;
            float f2 = 0.f;
#pragma unroll
            for (int k = 0; k < Kc; ++k) {
                float t  = (x - muk[k]) * rk[k];
                float tc = fminf(fmaxf(t, -4.f), 4.f);
                float y  = tc * tc;
                float a = fmaf(-2.72614225801306e-10f, y,  2.77068142495902e-08f);
                a = fmaf(a, y, -2.10102402082508e-06f);
                a = fmaf(a, y, -5.69250639462346e-05f);
                a = fmaf(a, y, -7.34990630326855e-04f);
                a = fmaf(a, y, -2.95459980854025e-03f);
                a = fmaf(a, y, -1.60960333262415e-02f);
                float b = fmaf(-1.45660718464996e-05f, y, -2.13374055278905e-04f);
                b = fmaf(b, y, -1.68282697438203e-03f);
                b = fmaf(b, y, -7.37332916720468e-03f);
                b = fmaf(b, y, -1.42647390514189e-02f);
                float e = (tc * a) * __builtin_amdgcn_rcpf(b);
                acc = fmaf(wh[k], e, acc);
                float g = ck[k] * __expf(-t * t);
                den = den + g;
                f2  = fmaf(g, t * rk[k], f2);
            }
            float r = acc - zv;
            conv = conv || (fabsf(r) <= 1.5e-3f * den);
            flat = flat || ((den < 1e-3f) && (it >= 1));
            bool active = !(conv || flat);
            if (__all(!active)) break;
            if (active) {
                bool gt = r > 0.f;
                if (gt) bhi = x; else blo = x;
                float invd = __builtin_amdgcn_rcpf(den);
                float nstep = r * invd;
                float hden = fmaf(nstep * invd, f2, 1.0f);
                hden = fminf(fmaxf(hden, 0.5f), 2.0f);
                float xn = x - nstep * __builtin_amdgcn_rcpf(hden);
                if (!(xn > blo && xn < bhi)) xn = 0.5f * (blo + bhi);
                x = xn;
            }
        }
        if (valid) {
            bool rescue = (!conv) || (den < 1e-3f);
            if (!rescue) {
                out_x[i]   = x;
                out_nld[i] = -__logf(den);
            } else {
                unsigned int idx = atomicAdd(&g_cnt_r, 1u);
                g_list_r[idx] = (unsigned int)i;
            }
        }
    }
}

// ---- k2: bit-exact R13 trajectory for rescue lanes ----
__global__ __launch_bounds__(256)
void k2_rescue(const float* __restrict__ z_in, const float* __restrict__ logits,
               const float* __restrict__ mu, const float* __restrict__ logstd,
               float* __restrict__ out_x, float* __restrict__ out_nld)
{
    unsigned int n = g_cnt_r;
    for (unsigned int j = blockIdx.x * 256 + threadIdx.x; j < n;
         j += gridDim.x * 256) {
        int i = (int)g_list_r[j];
        Params P;
        prep_params(i & (Dc - 1), logits, mu, logstd, P);
        float zv = fminf(fmaxf(z_in[i], 0.f), 1.f);
        float x, nld;
        traj_solve(zv, P, x, nld);
        out_x[i]   = x;
        out_nld[i] = nld;
    }
}

extern "C" void kernel_launch(void* const* d_in, const int* in_sizes, int n_in,
                              void* d_out, int out_size, void* d_ws, size_t ws_size,
                              hipStream_t stream) {
    const float* z      = (const float*)d_in[0];
    const float* logits = (const float*)d_in[1];
    const float* mu     = (const float*)d_in[2];
    const float* logstd = (const float*)d_in[3];
    float* out_x   = (float*)d_out;
    float* out_nld = (float*)d_out + Ntot;

    k0a_knots<<<(Dc * NKNOT + 255) / 256, 256, 0, stream>>>(logits, mu, logstd);
    k0b_cert<<<(Dc * NSEG * 5 + 255) / 256, 256, 0, stream>>>(logits, mu, logstd);
    k0c_pack<<<(Dc * NSEG + 255) / 256, 256, 0, stream>>>();
    k1_table<<<1024, 256, 0, stream>>>(z, out_x, out_nld);
    k1b_scan<<<(Ntot + 1023) / 1024, 256, 0, stream>>>(out_x);
    k1c_slow<<<512, 256, 0, stream>>>(z, logits, mu, logstd, out_x, out_nld);
    k2_rescue<<<512, 256, 0, stream>>>(z, logits, mu, logstd, out_x, out_nld);
}